// Round 1
// baseline (6142.426 us; speedup 1.0000x reference)
//
#include <hip/hip_runtime.h>
#include <hip/hip_bf16.h>
#include <math.h>

#define N_NODES 100000
#define D_IN 256
#define D_OUT 64
#define N_HEADS 4
#define P_TOTAL 5
#define NEDGE 3200000

// ---------------------------------------------------------------------------
// Zero-fill helper (avoid relying on any memset semantics under graph capture)
// ---------------------------------------------------------------------------
__global__ void zero_kernel(int* __restrict__ p, int n) {
    int i = blockIdx.x * blockDim.x + threadIdx.x;
    if (i < n) p[i] = 0;
}

// ---------------------------------------------------------------------------
// h = (shrink[m,i] @ x).T stored as H[m][n][ch], ch = i*64+d  (node-major)
// Register-tiled 64x64 tile, 256 threads, thread computes 4 nodes x 4 ch.
// ---------------------------------------------------------------------------
__global__ __launch_bounds__(256)
void gemm_h(const float* __restrict__ x, const float* __restrict__ W,
            float* __restrict__ H) {
    const int m  = blockIdx.z;
    const int c0 = blockIdx.y * 64;
    const int n0 = blockIdx.x * 64;
    __shared__ float xs[32][68];   // [k][n], pad to 272B rows (16B aligned)
    __shared__ float ws[32][68];   // [k][c]
    const int t  = threadIdx.x;
    const int c4 = (t & 15) * 4;   // consecutive lanes -> consecutive ch (coalesced writeback)
    const int n4 = (t >> 4) * 4;
    float acc[4][4];
#pragma unroll
    for (int a = 0; a < 4; ++a)
#pragma unroll
        for (int b = 0; b < 4; ++b) acc[a][b] = 0.f;

    for (int k0 = 0; k0 < 256; k0 += 32) {
#pragma unroll
        for (int it = 0; it < 8; ++it) {
            int idx = it * 256 + t;
            int kk = idx >> 6;          // 0..31
            int nn = idx & 63;
            int gn = n0 + nn;
            xs[kk][nn] = (gn < N_NODES) ? x[(size_t)(k0 + kk) * N_NODES + gn] : 0.f;
        }
#pragma unroll
        for (int it = 0; it < 8; ++it) {
            int idx = it * 256 + t;
            int cc = idx >> 5;          // 0..63
            int kk = idx & 31;
            ws[kk][cc] = W[((size_t)(m * 256 + c0 + cc)) * 256 + (k0 + kk)];
        }
        __syncthreads();
#pragma unroll
        for (int k = 0; k < 32; ++k) {
            float4 xv = *(const float4*)&xs[k][n4];
            float4 wv = *(const float4*)&ws[k][c4];
            float xa[4] = {xv.x, xv.y, xv.z, xv.w};
            float wa[4] = {wv.x, wv.y, wv.z, wv.w};
#pragma unroll
            for (int a = 0; a < 4; ++a)
#pragma unroll
                for (int b = 0; b < 4; ++b) acc[a][b] += xa[a] * wa[b];
        }
        __syncthreads();
    }
#pragma unroll
    for (int a = 0; a < 4; ++a) {
        int gn = n0 + n4 + a;
        if (gn < N_NODES) {
            float4 v4 = make_float4(acc[a][0], acc[a][1], acc[a][2], acc[a][3]);
            *(float4*)&H[((size_t)m * N_NODES + gn) * 256 + c0 + c4] = v4;
        }
    }
}

// ---------------------------------------------------------------------------
// A0[p][i][n] = h[m,n,i,:] . att0[p,i,:]   (and A1 likewise)
// one wave per (p,i,node): coalesced 256B read of h, two shuffle reductions
// ---------------------------------------------------------------------------
__global__ __launch_bounds__(256)
void att_kernel(const float* __restrict__ H, const float* __restrict__ att0,
                const float* __restrict__ att1, float* __restrict__ A0,
                float* __restrict__ A1) {
    const int pi   = blockIdx.y;          // p*4+i
    const int p    = pi >> 2;
    const int i    = pi & 3;
    const int m    = (p < 2) ? 0 : 1;
    const int wv   = threadIdx.x >> 6;
    const int lane = threadIdx.x & 63;
    const int n    = blockIdx.x * 4 + wv;
    float h  = H[((size_t)m * N_NODES + n) * 256 + i * 64 + lane];
    float t0 = h * att0[pi * 64 + lane];
    float t1 = h * att1[pi * 64 + lane];
#pragma unroll
    for (int off = 32; off > 0; off >>= 1) {
        t0 += __shfl_down(t0, off);
        t1 += __shfl_down(t1, off);
    }
    if (lane == 0) {
        A0[(size_t)pi * N_NODES + n] = t0;
        A1[(size_t)pi * N_NODES + n] = t1;
    }
}

// ---------------------------------------------------------------------------
// CSR build: histogram -> 3-phase exclusive scan -> scatter (c,v) pairs
// ---------------------------------------------------------------------------
__global__ __launch_bounds__(256)
void hist_kernel(const int* __restrict__ rows, int* __restrict__ counts) {
    const int p = blockIdx.y;
    const int e = blockIdx.x * 256 + threadIdx.x;
    int r = rows[(size_t)p * NEDGE + e];
    atomicAdd(&counts[p * N_NODES + r], 1);
}

__global__ __launch_bounds__(1024)
void scan1(const int* __restrict__ counts, int* __restrict__ rowstart,
           int* __restrict__ blocksum) {
    __shared__ int sh[1024];
    const int p = blockIdx.y, b = blockIdx.x, t = threadIdx.x;
    const int i = b * 1024 + t;
    int v = (i < N_NODES) ? counts[p * N_NODES + i] : 0;
    sh[t] = v;
    __syncthreads();
    for (int off = 1; off < 1024; off <<= 1) {
        int y = (t >= off) ? sh[t - off] : 0;
        __syncthreads();
        sh[t] += y;
        __syncthreads();
    }
    if (i < N_NODES) rowstart[p * (N_NODES + 1) + i] = sh[t] - v;  // exclusive
    if (t == 1023) blocksum[p * 128 + b] = sh[t];                  // block total
}

__global__ __launch_bounds__(128)
void scan2(int* __restrict__ blocksum, int* __restrict__ rowstart, int nb) {
    __shared__ int sh[128];
    const int p = blockIdx.x, t = threadIdx.x;
    int v = (t < nb) ? blocksum[p * 128 + t] : 0;
    sh[t] = v;
    __syncthreads();
    for (int off = 1; off < 128; off <<= 1) {
        int y = (t >= off) ? sh[t - off] : 0;
        __syncthreads();
        sh[t] += y;
        __syncthreads();
    }
    blocksum[p * 128 + t] = sh[t] - v;  // exclusive over block sums
    if (t == 0) rowstart[p * (N_NODES + 1) + N_NODES] = NEDGE;
}

__global__ __launch_bounds__(1024)
void scan3(int* __restrict__ rowstart, const int* __restrict__ blocksum) {
    const int p = blockIdx.y, b = blockIdx.x, t = threadIdx.x;
    const int i = b * 1024 + t;
    if (i < N_NODES) rowstart[p * (N_NODES + 1) + i] += blocksum[p * 128 + b];
}

__global__ __launch_bounds__(256)
void scatter_kernel(const int* __restrict__ rows, const int* __restrict__ cols,
                    const float* __restrict__ vals, const int* __restrict__ rowstart,
                    int* __restrict__ cursor, int2* __restrict__ cv) {
    const int p = blockIdx.y;
    const size_t base = (size_t)p * NEDGE;
    const size_t e = (size_t)blockIdx.x * 256 + threadIdx.x;
    int r = rows[base + e];
    int c = cols[base + e];
    float v = vals[base + e];
    int pos = rowstart[p * (N_NODES + 1) + r] + atomicAdd(&cursor[p * N_NODES + r], 1);
    cv[base + pos] = make_int2(c, __float_as_int(v));
}

// ---------------------------------------------------------------------------
// Main pass: block = 4 waves (one head each), lane = d, 16 rows per block.
// Per edge: broadcast (c,v), broadcast A0[c], coalesced 256B gather of h[c].
// exp(s) without max-subtraction (softmax shift-invariant, |s| small);
// division by denominator deferred to end of each row-segment.
// Output written through an LDS transpose tile for contiguous [ch][n] stores.
// ---------------------------------------------------------------------------
__global__ __launch_bounds__(256)
void row_pass(const float* __restrict__ H, const float* __restrict__ A0,
              const float* __restrict__ A1, const int* __restrict__ rowstart,
              const int2* __restrict__ cv, float* __restrict__ out) {
    const int m    = blockIdx.y;
    const int r0   = blockIdx.x * 16;
    const int i    = threadIdx.x >> 6;   // head
    const int lane = threadIdx.x & 63;   // d
    __shared__ float tile[4][16][65];
    const int p0 = (m == 0) ? 0 : 2;
    const int np = (m == 0) ? 2 : 3;
    const float* Hm = H + (size_t)m * N_NODES * 256;

    for (int rt = 0; rt < 16; ++rt) {
        const int r = r0 + rt;
        float acc = 0.f;
        for (int pk = 0; pk < np; ++pk) {
            const int p  = p0 + pk;
            const int pi = p * 4 + i;
            const int* rs = rowstart + p * (N_NODES + 1);
            const int e0 = rs[r], e1 = rs[r + 1];
            if (e1 > e0) {
                const float a1r = A1[(size_t)pi * N_NODES + r];
                const float* A0p = A0 + (size_t)pi * N_NODES;
                const int2* cvp = cv + (size_t)p * NEDGE;
                float den = 0.f, num = 0.f;
                for (int e = e0; e < e1; ++e) {
                    int2 ce = cvp[e];
                    int   c = ce.x;
                    float v = __int_as_float(ce.y);
                    float w = __expf(v * (A0p[c] + a1r));
                    den += w;
                    num += w * Hm[(size_t)c * 256 + i * 64 + lane];
                }
                acc += num / den;
            }
        }
        acc = acc > 0.f ? acc : __expf(acc) - 1.f;  // ELU
        tile[i][rt][lane] = acc;
    }
    __syncthreads();
    {
        const int ch = threadIdx.x;        // 0..255
        const int ii = ch >> 6, d = ch & 63;
        float* dst = out + ((size_t)m * 256 + ch) * N_NODES + r0;
#pragma unroll
        for (int q = 0; q < 4; ++q) {
            float4 v4 = make_float4(tile[ii][q * 4 + 0][d], tile[ii][q * 4 + 1][d],
                                    tile[ii][q * 4 + 2][d], tile[ii][q * 4 + 3][d]);
            *(float4*)(dst + q * 4) = v4;
        }
    }
}

// ---------------------------------------------------------------------------
extern "C" void kernel_launch(void* const* d_in, const int* in_sizes, int n_in,
                              void* d_out, int out_size, void* d_ws, size_t ws_size,
                              hipStream_t stream) {
    const float* x    = (const float*)d_in[0];
    const float* W    = (const float*)d_in[1];  // shrink_mats [2][4][64][256]
    const float* att0 = (const float*)d_in[2];  // [5][4][64]
    const float* att1 = (const float*)d_in[3];
    const int*   erows = (const int*)d_in[4];   // [5][E]
    const int*   ecols = (const int*)d_in[5];
    const float* evals = (const float*)d_in[6];
    float* out = (float*)d_out;                 // [2][256][N]

    char* ws = (char*)d_ws;
    size_t off = 0;
    auto alloc = [&](size_t bytes) -> void* {
        void* p = ws + off;
        off += (bytes + 255) & ~(size_t)255;
        return p;
    };
    float* H        = (float*)alloc((size_t)2 * N_NODES * 256 * 4);           // 204.8 MB
    float* A0       = (float*)alloc((size_t)P_TOTAL * N_HEADS * N_NODES * 4); // 8 MB
    float* A1       = (float*)alloc((size_t)P_TOTAL * N_HEADS * N_NODES * 4); // 8 MB
    int*   counts   = (int*)alloc((size_t)P_TOTAL * N_NODES * 4);             // 2 MB
    int*   cursor   = (int*)alloc((size_t)P_TOTAL * N_NODES * 4);             // 2 MB
    int*   rowstart = (int*)alloc((size_t)P_TOTAL * (N_NODES + 1) * 4);       // 2 MB
    int*   blocksum = (int*)alloc((size_t)P_TOTAL * 128 * 4);
    int2*  cv       = (int2*)alloc((size_t)P_TOTAL * NEDGE * 8);              // 128 MB
    (void)ws_size; (void)in_sizes; (void)n_in; (void)out_size;

    const int nb = (N_NODES + 1023) / 1024;  // 98

    {   // zero histogram counters + scatter cursors
        int zn = P_TOTAL * N_NODES;
        zero_kernel<<<(zn + 1023) / 1024, 1024, 0, stream>>>(counts, zn);
        zero_kernel<<<(zn + 1023) / 1024, 1024, 0, stream>>>(cursor, zn);
    }
    gemm_h<<<dim3((N_NODES + 63) / 64, 4, 2), 256, 0, stream>>>(x, W, H);
    att_kernel<<<dim3(N_NODES / 4, P_TOTAL * N_HEADS), 256, 0, stream>>>(H, att0, att1, A0, A1);
    hist_kernel<<<dim3(NEDGE / 256, P_TOTAL), 256, 0, stream>>>(erows, counts);
    scan1<<<dim3(nb, P_TOTAL), 1024, 0, stream>>>(counts, rowstart, blocksum);
    scan2<<<P_TOTAL, 128, 0, stream>>>(blocksum, rowstart, nb);
    scan3<<<dim3(nb, P_TOTAL), 1024, 0, stream>>>(rowstart, blocksum);
    scatter_kernel<<<dim3(NEDGE / 256, P_TOTAL), 256, 0, stream>>>(erows, ecols, evals,
                                                                   rowstart, cursor, cv);
    row_pass<<<dim3(N_NODES / 16, 2), 256, 0, stream>>>(H, A0, A1, rowstart, cv, out);
}

// Round 2
// 5174.929 us; speedup vs baseline: 1.1870x; 1.1870x over previous
//
#include <hip/hip_runtime.h>
#include <hip/hip_bf16.h>
#include <math.h>

#define N_NODES 100000
#define D_IN 256
#define D_OUT 64
#define N_HEADS 4
#define P_TOTAL 5
#define NEDGE 3200000

__device__ __forceinline__ unsigned short f2bf(float f) {
    unsigned u = __float_as_uint(f);
    unsigned r = (u + 0x7FFFu + ((u >> 16) & 1u)) >> 16;
    return (unsigned short)r;
}

// ---------------------------------------------------------------------------
__global__ void zero_kernel(int* __restrict__ p, int n) {
    int i = blockIdx.x * blockDim.x + threadIdx.x;
    if (i < n) p[i] = 0;
}

// ---------------------------------------------------------------------------
// h = (shrink[m,i] @ x).T  -> Hb bf16 [m][n][256]  (ch = i*64+d, node-major)
// Fused epilogue: A0[pi][n] = h . att0[pi], A1 likewise, from fp32 accs.
// blockIdx.y == head i (c0 = i*64), blockIdx.z == m.
// ---------------------------------------------------------------------------
__global__ __launch_bounds__(256)
void gemm_h(const float* __restrict__ x, const float* __restrict__ W,
            const float* __restrict__ att0, const float* __restrict__ att1,
            unsigned short* __restrict__ Hb,
            float* __restrict__ A0, float* __restrict__ A1) {
    const int m  = blockIdx.z;
    const int i  = blockIdx.y;        // head
    const int c0 = i * 64;
    const int n0 = blockIdx.x * 64;
    __shared__ float xs[32][68];
    __shared__ float ws[32][68];
    const int t  = threadIdx.x;
    const int c4 = (t & 15) * 4;
    const int n4 = (t >> 4) * 4;
    float acc[4][4];
#pragma unroll
    for (int a = 0; a < 4; ++a)
#pragma unroll
        for (int b = 0; b < 4; ++b) acc[a][b] = 0.f;

    for (int k0 = 0; k0 < 256; k0 += 32) {
#pragma unroll
        for (int it = 0; it < 8; ++it) {
            int idx = it * 256 + t;
            int kk = idx >> 6;
            int nn = idx & 63;
            int gn = n0 + nn;
            xs[kk][nn] = (gn < N_NODES) ? x[(size_t)(k0 + kk) * N_NODES + gn] : 0.f;
        }
#pragma unroll
        for (int it = 0; it < 8; ++it) {
            int idx = it * 256 + t;
            int cc = idx >> 5;
            int kk = idx & 31;
            ws[kk][cc] = W[((size_t)(m * 256 + c0 + cc)) * 256 + (k0 + kk)];
        }
        __syncthreads();
#pragma unroll
        for (int k = 0; k < 32; ++k) {
            float4 xv = *(const float4*)&xs[k][n4];
            float4 wv = *(const float4*)&ws[k][c4];
            float xa[4] = {xv.x, xv.y, xv.z, xv.w};
            float wa[4] = {wv.x, wv.y, wv.z, wv.w};
#pragma unroll
            for (int a = 0; a < 4; ++a)
#pragma unroll
                for (int b = 0; b < 4; ++b) acc[a][b] += xa[a] * wa[b];
        }
        __syncthreads();
    }
    // bf16 H writeback
#pragma unroll
    for (int a = 0; a < 4; ++a) {
        int gn = n0 + n4 + a;
        if (gn < N_NODES) {
            ushort4 s4;
            s4.x = f2bf(acc[a][0]); s4.y = f2bf(acc[a][1]);
            s4.z = f2bf(acc[a][2]); s4.w = f2bf(acc[a][3]);
            *(ushort4*)&Hb[((size_t)m * N_NODES + gn) * 256 + c0 + c4] = s4;
        }
    }
    // fused attention scalars (fp32 precision)
    const int p0 = m ? 2 : 0;
    const int np = m ? 3 : 2;
    for (int pk = 0; pk < np; ++pk) {
        const int pi = (p0 + pk) * 4 + i;
        float a0v[4], a1v[4];
#pragma unroll
        for (int b = 0; b < 4; ++b) {
            a0v[b] = att0[pi * 64 + c4 + b];
            a1v[b] = att1[pi * 64 + c4 + b];
        }
#pragma unroll
        for (int a = 0; a < 4; ++a) {
            float s0 = 0.f, s1 = 0.f;
#pragma unroll
            for (int b = 0; b < 4; ++b) {
                s0 += acc[a][b] * a0v[b];
                s1 += acc[a][b] * a1v[b];
            }
#pragma unroll
            for (int off = 1; off < 16; off <<= 1) {
                s0 += __shfl_xor(s0, off);
                s1 += __shfl_xor(s1, off);
            }
            int gn = n0 + n4 + a;
            if ((t & 15) == 0 && gn < N_NODES) {
                A0[(size_t)pi * N_NODES + gn] = s0;
                A1[(size_t)pi * N_NODES + gn] = s1;
            }
        }
    }
}

// ---------------------------------------------------------------------------
// CSR build: histogram -> 3-phase exclusive scan -> scatter packed (c,v) u32
// ---------------------------------------------------------------------------
__global__ __launch_bounds__(256)
void hist_kernel(const int* __restrict__ rows, int* __restrict__ counts) {
    const int p = blockIdx.y;
    const int e = blockIdx.x * 256 + threadIdx.x;
    int r = rows[(size_t)p * NEDGE + e];
    atomicAdd(&counts[p * N_NODES + r], 1);
}

__global__ __launch_bounds__(1024)
void scan1(const int* __restrict__ counts, int* __restrict__ rowstart,
           int* __restrict__ blocksum) {
    __shared__ int sh[1024];
    const int p = blockIdx.y, b = blockIdx.x, t = threadIdx.x;
    const int i = b * 1024 + t;
    int v = (i < N_NODES) ? counts[p * N_NODES + i] : 0;
    sh[t] = v;
    __syncthreads();
    for (int off = 1; off < 1024; off <<= 1) {
        int y = (t >= off) ? sh[t - off] : 0;
        __syncthreads();
        sh[t] += y;
        __syncthreads();
    }
    if (i < N_NODES) rowstart[p * (N_NODES + 1) + i] = sh[t] - v;
    if (t == 1023) blocksum[p * 128 + b] = sh[t];
}

__global__ __launch_bounds__(128)
void scan2(int* __restrict__ blocksum, int* __restrict__ rowstart, int nb) {
    __shared__ int sh[128];
    const int p = blockIdx.x, t = threadIdx.x;
    int v = (t < nb) ? blocksum[p * 128 + t] : 0;
    sh[t] = v;
    __syncthreads();
    for (int off = 1; off < 128; off <<= 1) {
        int y = (t >= off) ? sh[t - off] : 0;
        __syncthreads();
        sh[t] += y;
        __syncthreads();
    }
    blocksum[p * 128 + t] = sh[t] - v;
    if (t == 0) rowstart[p * (N_NODES + 1) + N_NODES] = NEDGE;
}

__global__ __launch_bounds__(1024)
void scan3(int* __restrict__ rowstart, const int* __restrict__ blocksum) {
    const int p = blockIdx.y, b = blockIdx.x, t = threadIdx.x;
    const int i = b * 1024 + t;
    if (i < N_NODES) rowstart[p * (N_NODES + 1) + i] += blocksum[p * 128 + b];
}

__global__ __launch_bounds__(256)
void scatter_kernel(const int* __restrict__ rows, const int* __restrict__ cols,
                    const float* __restrict__ vals, const int* __restrict__ rowstart,
                    int* __restrict__ cursor, unsigned* __restrict__ cv) {
    const int p = blockIdx.y;
    const size_t base = (size_t)p * NEDGE;
    const size_t e = (size_t)blockIdx.x * 256 + threadIdx.x;
    int r = rows[base + e];
    int c = cols[base + e];
    float v = vals[base + e];
    int q = (int)(v * 32768.0f + 0.5f);
    if (q > 32767) q = 32767;
    unsigned cu = ((unsigned)c << 15) | (unsigned)q;
    int pos = rowstart[p * (N_NODES + 1) + r] + atomicAdd(&cursor[p * N_NODES + r], 1);
    cv[base + pos] = cu;
}

// ---------------------------------------------------------------------------
// Main pass: block = 4 waves (one head each); wave splits into two halves,
// each half processes alternate edges (2 edges in flight per wave).
// Lane l (0..31) of each half holds channels d = 2l, 2l+1 (bf16x2 gather).
// Softmax denominator division deferred per (row, position); combine halves
// with one shfl_xor(32) per position.
// ---------------------------------------------------------------------------
__global__ __launch_bounds__(256)
void row_pass(const unsigned short* __restrict__ Hb, const float* __restrict__ A0,
              const float* __restrict__ A1, const int* __restrict__ rowstart,
              const unsigned* __restrict__ cv, float* __restrict__ out) {
    const int m    = blockIdx.y;
    const int r0   = blockIdx.x * 16;
    const int i    = threadIdx.x >> 6;   // head
    const int lane = threadIdx.x & 63;
    const int half = lane >> 5;
    const int l    = lane & 31;
    __shared__ float tile[4][16][66];
    const int p0 = m ? 2 : 0;
    const int np = m ? 3 : 2;
    const unsigned* Hm32 = (const unsigned*)(Hb + (size_t)m * N_NODES * 256);
    const int hoff = i * 32 + l;   // u32 offset within a 128-u32 H row

    for (int rt = 0; rt < 16; ++rt) {
        const int r = r0 + rt;
        float acc0 = 0.f, acc1 = 0.f;
        for (int pk = 0; pk < np; ++pk) {
            const int p  = p0 + pk;
            const int pi = p * 4 + i;
            const int* rs = rowstart + p * (N_NODES + 1);
            const int e0 = rs[r], e1 = rs[r + 1];
            if (e1 > e0) {
                const float a1r = A1[(size_t)pi * N_NODES + r];
                const float* A0p = A0 + (size_t)pi * N_NODES;
                const unsigned* cvp = cv + (size_t)p * NEDGE;
                float den = 0.f, num0 = 0.f, num1 = 0.f;
                for (int e = e0 + half; e < e1; e += 2) {
                    unsigned cu = cvp[e];
                    int   c = (int)(cu >> 15);
                    float v = (float)(cu & 32767u) * (1.0f / 32768.0f);
                    float w = __expf(v * (A0p[c] + a1r));
                    unsigned hu = Hm32[(size_t)c * 128 + hoff];
                    float h0 = __uint_as_float(hu << 16);
                    float h1 = __uint_as_float(hu & 0xFFFF0000u);
                    den  += w;
                    num0 += w * h0;
                    num1 += w * h1;
                }
                float dt  = den  + __shfl_xor(den, 32);
                float n0t = num0 + __shfl_xor(num0, 32);
                float n1t = num1 + __shfl_xor(num1, 32);
                acc0 += n0t / dt;
                acc1 += n1t / dt;
            }
        }
        acc0 = acc0 > 0.f ? acc0 : __expf(acc0) - 1.f;  // ELU
        acc1 = acc1 > 0.f ? acc1 : __expf(acc1) - 1.f;
        if (half == 0)
            *(float2*)&tile[i][rt][2 * l] = make_float2(acc0, acc1);
    }
    __syncthreads();
    {
        const int ch = threadIdx.x;
        const int ii = ch >> 6, d = ch & 63;
        float* dst = out + ((size_t)m * 256 + ch) * N_NODES + r0;
#pragma unroll
        for (int q = 0; q < 4; ++q) {
            float4 v4 = make_float4(tile[ii][q * 4 + 0][d], tile[ii][q * 4 + 1][d],
                                    tile[ii][q * 4 + 2][d], tile[ii][q * 4 + 3][d]);
            *(float4*)(dst + q * 4) = v4;
        }
    }
}

// ---------------------------------------------------------------------------
extern "C" void kernel_launch(void* const* d_in, const int* in_sizes, int n_in,
                              void* d_out, int out_size, void* d_ws, size_t ws_size,
                              hipStream_t stream) {
    const float* x    = (const float*)d_in[0];
    const float* W    = (const float*)d_in[1];
    const float* att0 = (const float*)d_in[2];
    const float* att1 = (const float*)d_in[3];
    const int*   erows = (const int*)d_in[4];
    const int*   ecols = (const int*)d_in[5];
    const float* evals = (const float*)d_in[6];
    float* out = (float*)d_out;

    char* ws = (char*)d_ws;
    size_t off = 0;
    auto alloc = [&](size_t bytes) -> void* {
        void* p = ws + off;
        off += (bytes + 255) & ~(size_t)255;
        return p;
    };
    unsigned short* Hb = (unsigned short*)alloc((size_t)2 * N_NODES * 256 * 2);   // 102.4 MB
    float* A0       = (float*)alloc((size_t)P_TOTAL * N_HEADS * N_NODES * 4);     // 8 MB
    float* A1       = (float*)alloc((size_t)P_TOTAL * N_HEADS * N_NODES * 4);     // 8 MB
    int*   counts   = (int*)alloc((size_t)P_TOTAL * N_NODES * 4);
    int*   cursor   = (int*)alloc((size_t)P_TOTAL * N_NODES * 4);
    int*   rowstart = (int*)alloc((size_t)P_TOTAL * (N_NODES + 1) * 4);
    int*   blocksum = (int*)alloc((size_t)P_TOTAL * 128 * 4);
    unsigned* cv    = (unsigned*)alloc((size_t)P_TOTAL * NEDGE * 4);              // 64 MB
    (void)ws_size; (void)in_sizes; (void)n_in; (void)out_size;

    const int nb = (N_NODES + 1023) / 1024;

    {
        int zn = P_TOTAL * N_NODES;
        zero_kernel<<<(zn + 1023) / 1024, 1024, 0, stream>>>(counts, zn);
        zero_kernel<<<(zn + 1023) / 1024, 1024, 0, stream>>>(cursor, zn);
    }
    gemm_h<<<dim3((N_NODES + 63) / 64, 4, 2), 256, 0, stream>>>(x, W, att0, att1, Hb, A0, A1);
    hist_kernel<<<dim3(NEDGE / 256, P_TOTAL), 256, 0, stream>>>(erows, counts);
    scan1<<<dim3(nb, P_TOTAL), 1024, 0, stream>>>(counts, rowstart, blocksum);
    scan2<<<P_TOTAL, 128, 0, stream>>>(blocksum, rowstart, nb);
    scan3<<<dim3(nb, P_TOTAL), 1024, 0, stream>>>(rowstart, blocksum);
    scatter_kernel<<<dim3(NEDGE / 256, P_TOTAL), 256, 0, stream>>>(erows, ecols, evals,
                                                                   rowstart, cursor, cv);
    row_pass<<<dim3(N_NODES / 16, 2), 256, 0, stream>>>(Hb, A0, A1, rowstart, cv, out);
}